// Round 1
// baseline (226.002 us; speedup 1.0000x reference)
//
#include <hip/hip_runtime.h>

typedef float v2f __attribute__((ext_vector_type(2)));

#define NW 16
#define NBATCH 256
#define QDIM 65536

// ---------------------------------------------------------------------------
// LDS swizzle: l ^ ((l>>5)&31) -- gives perfect 4-way bank-pair spread (free
// for b64) on every remap read/write pattern used below.
__device__ __forceinline__ int swz(int l) { return l ^ ((l >> 5) & 31); }

// SU(2) rotation on a register pair: U = [[a, b], [-conj(b), conj(a)]]
//   n0 = a*x + b*y ; n1 = -conj(b)*x + conj(a)*y   (complex, packed as v2f)
__device__ __forceinline__ void rot2(v2f& x, v2f& y, v2f aa, v2f an, v2f bb, v2f bn) {
  v2f xs = __builtin_shufflevector(x, x, 1, 0);
  v2f ys = __builtin_shufflevector(y, y, 1, 0);
  v2f n0 = aa * x + an * xs + bb * y + bn * ys;
  v2f n1 = aa * y - an * ys + bn * xs - bb * x;
  x = n0;
  y = n1;
}

// Rotation gate on window-local bit T, gate table index G (uniform).
#define ROT(T, G)                                                              \
  do {                                                                         \
    const float4 u = Utab[G];                                                  \
    const v2f aa = {u.x, u.x}, an = {-u.y, u.y};                               \
    const v2f bb = {u.z, u.z}, bn = {-u.w, u.w};                               \
    _Pragma("unroll") for (int v = 0; v < 32; ++v) if (!((v >> (T)) & 1))      \
        rot2(s[v], s[v | (1 << (T))], aa, an, bb, bn);                         \
  } while (0)

// CNOT with control bit C, target bit T, both in window: compile-time
// register swap -> SSA renaming, zero instructions.
#define CNOTW(C, T)                                                            \
  do {                                                                         \
    _Pragma("unroll") for (int v = 0; v < 32; ++v)                             \
        if (((v >> (C)) & 1) && !((v >> (T)) & 1)) {                           \
      v2f tmp = s[v];                                                          \
      s[v] = s[v | (1 << (T))];                                                \
      s[v | (1 << (T))] = tmp;                                                 \
    }                                                                          \
  } while (0)

// Window maps: local 13-bit index from (tid[7:0], reg v[4:0]).
#define MAP_W1(t, v) (((v) << 8) | (t))                              // reg = bits 12..8
#define MAP_W2(t, v) ((((t) >> 4) << 9) | ((v) << 4) | ((t) & 15))   // reg = bits 8..4
#define MAP_W3(t, v) (((t) << 5) | (v))                              // reg = bits 4..0
#define MAP_M1(t, v) ((((t) >> 1) << 6) | ((v) << 1) | ((t) & 1))    // reg = bits 5..1
#define MAP_M2(t, v) ((((t) >> 2) << 7) | ((v) << 2) | ((t) & 3))    // reg = bits 6..2

// Slide the register window: write with old map, read with new map.
#define REMAP(MW, MR)                                                          \
  do {                                                                         \
    _Pragma("unroll") for (int r = 0; r < 32; ++r)                             \
        lds2[swz(MW(tid, r))] = s[r];                                          \
    __syncthreads();                                                           \
    _Pragma("unroll") for (int v = 0; v < 32; ++v)                             \
        s[v] = lds2[swz(MR(tid, v))];                                          \
    __syncthreads();                                                           \
  } while (0)

// ---------------------------------------------------------------------------
// Setup: fused U = RZ(rz) @ RY(ry) @ RX(rx) per (layer, wire), stored as
// (alpha_re, alpha_im, beta_re, beta_im); U = [[a,b],[-conj(b),conj(a)]].
__global__ void k_setup(const float* __restrict__ params, float4* __restrict__ Utab) {
  int g = threadIdx.x;
  if (g < 64) {
    float a = params[g * 3 + 0] * 0.5f;
    float b = params[g * 3 + 1] * 0.5f;
    float c = params[g * 3 + 2] * 0.5f;
    float sa, ca, sb, cb, sc, cc;
    sincosf(a, &sa, &ca);
    sincosf(b, &sb, &cb);
    sincosf(c, &sc, &cc);
    // M = RY@RX: M00 = cb*ca + i sb*sa ; M01 = -sb*ca - i cb*sa
    float X = cb * ca, Y = sb * sa;
    float Xp = -sb * ca, Yp = -cb * sa;
    // alpha = e^{-ic} * M00, beta = e^{-ic} * M01
    Utab[g] = make_float4(cc * X + sc * Y, cc * Y - sc * X,
                          cc * Xp + sc * Yp, cc * Yp - sc * Xp);
  }
}

// ---------------------------------------------------------------------------
// Pass A: local wires 0..12 (index bits 15..3). WG = (b, g=bits 2..0).
// Executes R_l(0..12-l) and C_l(0..11-l) for l=0..3 (staircase light-cone).
// Local bit for wire q is (12-q).
__global__ __launch_bounds__(256, 2) void k_passA(const float* __restrict__ in,
                                                  const float4* __restrict__ Utab,
                                                  v2f* __restrict__ st) {
  __shared__ v2f lds2[8192];
  const int tid = threadIdx.x;
  const int g = blockIdx.x >> 8;    // bits 2..0 of original index
  const int b = blockIdx.x & 255;   // batch  (siblings of b share an XCD)
  const float* base = in + (size_t)b * QDIM;

  v2f s[32];
  // Direct load in W1 arrangement (reg = local bits 12..8): strided by 8 f32.
#pragma unroll
  for (int v = 0; v < 32; ++v) {
    float re = base[(MAP_W1(tid, v) << 3) | g];
    s[v] = v2f{re, 0.0f};
  }

  for (int l = 0; l < 4; ++l) {
    // ---- W1: reg = local bits 12..8 (wires 0..4); T = 4-q
    ROT(4, l * 16 + 0); ROT(3, l * 16 + 1); ROT(2, l * 16 + 2);
    ROT(1, l * 16 + 3); ROT(0, l * 16 + 4);
    CNOTW(4, 3); CNOTW(3, 2); CNOTW(2, 1); CNOTW(1, 0);   // C[l][0..3]
    REMAP(MAP_W1, MAP_W2);
    // ---- W2: reg = local bits 8..4 (wires 4..8); rot T = 7-q... wires 5..8 -> T 3..0
    ROT(3, l * 16 + 5); ROT(2, l * 16 + 6); ROT(1, l * 16 + 7); ROT(0, l * 16 + 8);
    CNOTW(4, 3); CNOTW(3, 2); CNOTW(2, 1); CNOTW(1, 0);   // C[l][4..7]
    REMAP(MAP_W2, MAP_W3);
    // ---- W3: reg = local bits 4..0 (wires 8..12); staircase tail
    ROT(3, l * 16 + 9);
    if (l <= 2) ROT(2, l * 16 + 10);
    if (l <= 1) ROT(1, l * 16 + 11);
    if (l == 0) ROT(0, l * 16 + 12);
    CNOTW(4, 3);                    // C[l][8]
    if (l <= 2) CNOTW(3, 2);        // C[l][9]
    if (l <= 1) CNOTW(2, 1);        // C[l][10]
    if (l == 0) CNOTW(1, 0);        // C[l][11]
    if (l < 3) REMAP(MAP_W3, MAP_W1);
  }

  // Store via LDS bounce for per-instruction coalescing.
  // Intermediate layout within b: addr = g*8192 + (i>>3)  (i = original index)
#pragma unroll
  for (int r = 0; r < 32; ++r) lds2[swz(MAP_W3(tid, r))] = s[r];
  __syncthreads();
  v2f* outp = st + (size_t)(b * 8 + g) * 8192;
#pragma unroll
  for (int k = 0; k < 32; ++k) outp[k * 256 + tid] = lds2[swz(k * 256 + tid)];
}

// ---------------------------------------------------------------------------
// Pass B: local wires 3..15 (index bits 12..0). WG = (b, h=bits 15..13).
// All remaining ops touch local bits 6..0. Local bit for wire q is (15-q).
// Ends with probs -> per-wire Z expectation partials.
__global__ __launch_bounds__(256, 2) void k_passB(const v2f* __restrict__ st,
                                                  const float4* __restrict__ Utab,
                                                  float* __restrict__ partials) {
  __shared__ v2f lds2[8192];
  const int tid = threadIdx.x;
  const int b = blockIdx.x >> 3;
  const int h = blockIdx.x & 7;
  const v2f* base = st + (size_t)b * 8 * 8192;

  // Coalesced load of 8 chunks (chunk j at j*8192 + h*1024), bounce via LDS.
#pragma unroll
  for (int k = 0; k < 32; ++k) {
    int o = k * 256 + tid;
    v2f val = base[((o >> 10) << 13) + (h << 10) + (o & 1023)];
    lds2[swz(((o & 1023) << 3) | (o >> 10))] = val;  // c = local 13-bit index
  }
  __syncthreads();
  v2f s[32];
#pragma unroll
  for (int v = 0; v < 32; ++v) s[v] = lds2[swz(MAP_W3(tid, v))];
  __syncthreads();

  // ---- M0: reg = c bits 4..0
  ROT(2, 13); ROT(1, 14); ROT(0, 15);                      // R[0] w13..15
  CNOTW(3, 2); CNOTW(2, 1); CNOTW(1, 0);                   // C[0] q12..14
  ROT(3, 16 + 12); ROT(2, 16 + 13); ROT(1, 16 + 14); ROT(0, 16 + 15); // R[1] w12..15
  CNOTW(4, 3); CNOTW(3, 2); CNOTW(2, 1); CNOTW(1, 0);      // C[1] q11..14
  ROT(4, 32 + 11); ROT(3, 32 + 12); ROT(2, 32 + 13);
  ROT(1, 32 + 14); ROT(0, 32 + 15);                        // R[2] w11..15
  REMAP(MAP_W3, MAP_M1);
  // ---- M1: reg = c bits 5..1 (local T = bit-1)
  CNOTW(4, 3); CNOTW(3, 2); CNOTW(2, 1); CNOTW(1, 0);      // C[2] q10..13
  ROT(4, 48 + 10); ROT(3, 48 + 11); ROT(2, 48 + 12); ROT(1, 48 + 13); // R[3] w10..13
  REMAP(MAP_M1, MAP_M2);
  // ---- M2: reg = c bits 6..2 (local T = bit-2)
  CNOTW(4, 3); CNOTW(3, 2); CNOTW(2, 1); CNOTW(1, 0);      // C[3] q9..12
  REMAP(MAP_M2, MAP_W3);
  // ---- M3: reg = c bits 4..0
  CNOTW(1, 0);                                             // C[2] q14
  ROT(1, 48 + 14); ROT(0, 48 + 15);                        // R[3] w14, w15
  CNOTW(2, 1);                                             // C[3] q13
  CNOTW(1, 0);                                             // C[3] q14

  // ---- Epilogue: probs and per-wire signed sums.
  // c = (tid<<5)|r : wires 11..15 <-> r bits 4..0 ; wires 3..10 <-> tid bits 7..0
  float P = 0.f, f11 = 0.f, f12 = 0.f, f13 = 0.f, f14 = 0.f, f15 = 0.f;
#pragma unroll
  for (int r = 0; r < 32; ++r) {
    float p = s[r][0] * s[r][0] + s[r][1] * s[r][1];
    P += p;
    f11 += ((r >> 4) & 1) ? -p : p;
    f12 += ((r >> 3) & 1) ? -p : p;
    f13 += ((r >> 2) & 1) ? -p : p;
    f14 += ((r >> 1) & 1) ? -p : p;
    f15 += ((r >> 0) & 1) ? -p : p;
  }
  float vals[14];
  vals[0] = P;
#pragma unroll
  for (int q = 3; q <= 10; ++q)  // wire q <-> tid bit (10-q)
    vals[q - 2] = ((tid >> (10 - q)) & 1) ? -P : P;
  vals[9] = f11; vals[10] = f12; vals[11] = f13; vals[12] = f14; vals[13] = f15;

  float* red = (float*)lds2;
#pragma unroll
  for (int q = 0; q < 14; ++q) red[q * 256 + tid] = vals[q];
  __syncthreads();
  for (int off = 128; off > 0; off >>= 1) {
    if (tid < off) {
#pragma unroll
      for (int q = 0; q < 14; ++q) red[q * 256 + tid] += red[q * 256 + tid + off];
    }
    __syncthreads();
  }
  if (tid == 0) {
    float Pt = red[0];
    float* pt = partials + (size_t)blockIdx.x * 16;
    pt[0] = (h & 4) ? -Pt : Pt;   // wire 0 <-> h bit 2
    pt[1] = (h & 2) ? -Pt : Pt;   // wire 1 <-> h bit 1
    pt[2] = (h & 1) ? -Pt : Pt;   // wire 2 <-> h bit 0
#pragma unroll
    for (int q = 3; q <= 15; ++q) pt[q] = red[(q - 2) * 256];
  }
}

// ---------------------------------------------------------------------------
__global__ void k_head(const float* __restrict__ partials, const float* __restrict__ w,
                       const float* __restrict__ bh, float* __restrict__ out) {
  int b = threadIdx.x;  // 256 threads
  float acc = bh[0];
  for (int q = 0; q < 16; ++q) {
    float F = 0.f;
    for (int hh = 0; hh < 8; ++hh) F += partials[(size_t)(b * 8 + hh) * 16 + q];
    acc += w[q] * F;
  }
  out[b] = acc;
}

// ---------------------------------------------------------------------------
extern "C" void kernel_launch(void* const* d_in, const int* in_sizes, int n_in,
                              void* d_out, int out_size, void* d_ws, size_t ws_size,
                              hipStream_t stream) {
  const float* state  = (const float*)d_in[0];
  const float* params = (const float*)d_in[1];
  const float* w_head = (const float*)d_in[2];
  const float* b_head = (const float*)d_in[3];
  float* out = (float*)d_out;

  char* ws = (char*)d_ws;
  // ws layout: [0,128MB) intermediate state ; +1KB U table ; +128KB partials
  v2f* st = (v2f*)ws;
  float4* Utab = (float4*)(ws + (size_t)134217728);
  float* partials = (float*)(ws + (size_t)134217728 + 1024);

  k_setup<<<1, 64, 0, stream>>>(params, Utab);
  k_passA<<<dim3(2048), dim3(256), 0, stream>>>(state, Utab, st);
  k_passB<<<dim3(2048), dim3(256), 0, stream>>>(st, Utab, partials);
  k_head<<<1, 256, 0, stream>>>(partials, w_head, b_head, out);
}

// Round 2
// 215.084 us; speedup vs baseline: 1.0508x; 1.0508x over previous
//
#include <hip/hip_runtime.h>

typedef float v2f __attribute__((ext_vector_type(2)));

#define NT 512   // threads per block
#define NR 16    // v2f amplitudes per thread (4-bit register window)

// ---------------------------------------------------------------------------
// LDS swizzle: l ^ ((l>>5)&31) -- verified 2-per-bank-pair (free for b64) on
// every map pattern below (round 1 measured SQ_LDS_BANK_CONFLICT = 0).
__device__ __forceinline__ int swz(int l) { return l ^ ((l >> 5) & 31); }

// SU(2) rotation on a register pair: U = [[a, b], [-conj(b), conj(a)]]
__device__ __forceinline__ void rot2(v2f& x, v2f& y, v2f aa, v2f an, v2f bb, v2f bn) {
  v2f xs = __builtin_shufflevector(x, x, 1, 0);
  v2f ys = __builtin_shufflevector(y, y, 1, 0);
  v2f n0 = aa * x + an * xs + bb * y + bn * ys;
  v2f n1 = aa * y - an * ys + bn * xs - bb * x;
  x = n0;
  y = n1;
}

#define ROT(T, G)                                                              \
  do {                                                                         \
    const float4 u = Utab[G];                                                  \
    const v2f aa = {u.x, u.x}, an = {-u.y, u.y};                               \
    const v2f bb = {u.z, u.z}, bn = {-u.w, u.w};                               \
    _Pragma("unroll") for (int v = 0; v < NR; ++v) if (!((v >> (T)) & 1))      \
        rot2(s[v], s[v | (1 << (T))], aa, an, bb, bn);                         \
  } while (0)

// CNOT, both bits in window: compile-time register swap (zero instructions).
#define CNOTW(C, T)                                                            \
  do {                                                                         \
    _Pragma("unroll") for (int v = 0; v < NR; ++v)                             \
        if (((v >> (C)) & 1) && !((v >> (T)) & 1)) {                           \
      v2f tmp = s[v];                                                          \
      s[v] = s[v | (1 << (T))];                                                \
      s[v | (1 << (T))] = tmp;                                                 \
    }                                                                          \
  } while (0)

// Window maps: 13-bit local index from (t[8:0], reg v[3:0]).
#define MAP_A1(t, v) (((v) << 9) | (t))                               // reg = bits 12..9
#define MAP_A2(t, v) ((((t) >> 6) << 10) | ((v) << 6) | ((t) & 63))   // reg = bits 9..6
#define MAP_A3(t, v) ((((t) >> 3) << 7) | ((v) << 3) | ((t) & 7))     // reg = bits 6..3
#define MAP_A4(t, v) (((t) << 4) | (v))                               // reg = bits 3..0
#define MAP_B2(t, v) ((((t) >> 2) << 6) | ((v) << 2) | ((t) & 3))     // reg = bits 5..2
#define MAP_B3(t, v) ((((t) >> 1) << 5) | ((v) << 1) | ((t) & 1))     // reg = bits 4..1

#define REMAP(MW, MR)                                                          \
  do {                                                                         \
    _Pragma("unroll") for (int r = 0; r < NR; ++r)                             \
        lds2[swz(MW(tid, r))] = s[r];                                          \
    __syncthreads();                                                           \
    _Pragma("unroll") for (int v = 0; v < NR; ++v)                             \
        s[v] = lds2[swz(MR(tid, v))];                                          \
    __syncthreads();                                                           \
  } while (0)

// ---------------------------------------------------------------------------
// Fused U = RZ @ RY @ RX per (layer, wire): (alpha_re, alpha_im, beta_re, beta_im)
__global__ void k_setup(const float* __restrict__ params, float4* __restrict__ Utab) {
  int g = threadIdx.x;
  if (g < 64) {
    float a = params[g * 3 + 0] * 0.5f;
    float b = params[g * 3 + 1] * 0.5f;
    float c = params[g * 3 + 2] * 0.5f;
    float sa, ca, sb, cb, sc, cc;
    sincosf(a, &sa, &ca);
    sincosf(b, &sb, &cb);
    sincosf(c, &sc, &cc);
    float X = cb * ca, Y = sb * sa;
    float Xp = -sb * ca, Yp = -cb * sa;
    Utab[g] = make_float4(cc * X + sc * Y, cc * Y - sc * X,
                          cc * Xp + sc * Yp, cc * Yp - sc * Xp);
  }
}

// ---------------------------------------------------------------------------
// Pass A: local wires 0..12 (orig bits 15..3); wire q <-> local bit 12-q.
// Staircase: executes R_l on wires 0..12-l, C_l pairs (q,q+1) for q <= 11-l.
__global__ __launch_bounds__(NT, 4) void k_passA(const float* __restrict__ in,
                                                 const float4* __restrict__ Utab,
                                                 v2f* __restrict__ st) {
  __shared__ v2f lds2[8192];
  const int tid = threadIdx.x;
  // XCD grouping: all 8 g-siblings of batch b on one XCD, consecutive slots.
  const int g = (blockIdx.x >> 3) & 7;
  const int b = ((blockIdx.x >> 6) << 3) | (blockIdx.x & 7);
  const float* base = in + (size_t)b * 65536;

  v2f s[NR];
  // Direct load in A1 arrangement: float idx = v*4096 + t*8 + g (stride-8;
  // the 8 same-XCD siblings cover each line -> L2 reuse).
#pragma unroll
  for (int v = 0; v < NR; ++v) {
    float re = base[(v << 12) + (tid << 3) + g];
    s[v] = v2f{re, 0.0f};
  }

#pragma unroll
  for (int l = 0; l < 4; ++l) {
    // W1: reg bits 12..9 = wires 0..3 (T = 3-q)
    ROT(3, l * 16 + 0); ROT(2, l * 16 + 1); ROT(1, l * 16 + 2); ROT(0, l * 16 + 3);
    CNOTW(3, 2); CNOTW(2, 1); CNOTW(1, 0);       // C_l (0,1),(1,2),(2,3)
    REMAP(MAP_A1, MAP_A2);
    // W2: reg bits 9..6 = wires 3..6; rotations on 4,5,6 (T = 6-q)
    ROT(2, l * 16 + 4); ROT(1, l * 16 + 5); ROT(0, l * 16 + 6);
    CNOTW(3, 2); CNOTW(2, 1); CNOTW(1, 0);       // C_l (3,4),(4,5),(5,6)
    REMAP(MAP_A2, MAP_A3);
    // W3: reg bits 6..3 = wires 6..9; rotations on 7,8,9 (T = 9-q)
    ROT(2, l * 16 + 7); ROT(1, l * 16 + 8); ROT(0, l * 16 + 9);
    CNOTW(3, 2); CNOTW(2, 1); CNOTW(1, 0);       // C_l (6,7),(7,8),(8,9)
    if (l < 3) {
      REMAP(MAP_A3, MAP_A4);
      // W4: reg bits 3..0 = wires 9..12 (T = 12-q); staircase tail
      ROT(2, l * 16 + 10);                       // wire 10, l<=2
      if (l <= 1) ROT(1, l * 16 + 11);           // wire 11
      if (l == 0) ROT(0, l * 16 + 12);           // wire 12
      CNOTW(3, 2);                               // (9,10), l<=2
      if (l <= 1) CNOTW(2, 1);                   // (10,11)
      if (l == 0) CNOTW(1, 0);                   // (11,12)
      REMAP(MAP_A4, MAP_A1);
    }
  }

  // Store bounce (from A3 arrangement): intermediate layout within batch b:
  // chunk g holds m = orig>>3 at offset m; addr = (b*8+g)*8192 + m.
#pragma unroll
  for (int r = 0; r < NR; ++r) lds2[swz(MAP_A3(tid, r))] = s[r];
  __syncthreads();
  float4* outp = (float4*)(st + (size_t)(b * 8 + g) * 8192);
#pragma unroll
  for (int k = 0; k < 8; ++k) {
    int o = (k << 10) + (tid << 1);
    v2f a0 = lds2[swz(o)], a1 = lds2[swz(o + 1)];
    outp[(k << 9) + tid] = make_float4(a0[0], a0[1], a1[0], a1[1]);
  }
}

// ---------------------------------------------------------------------------
// Pass B: local wires 3..15 (orig bits 12..0); wire q <-> local bit 15-q.
// Remaining ops touch bits 6..0. CNOT chains force diagonal window slide:
// P0(3..0) -> P1(6..3) -> P2(5..2) -> P3(4..1) -> P4(3..0).
__global__ __launch_bounds__(NT, 4) void k_passB(const v2f* __restrict__ st,
                                                 const float4* __restrict__ Utab,
                                                 float* __restrict__ partials) {
  __shared__ v2f lds2[8192];
  const int tid = threadIdx.x;
  const int b = blockIdx.x >> 3;
  const int h = blockIdx.x & 7;  // orig bits 15..13
  const float4* base4 = (const float4*)(st + (size_t)b * 65536);

  // Coalesced float4 load; element i of chunk k has c = (i<<3)|k.
#pragma unroll
  for (int k = 0; k < 8; ++k) {
    float4 val = base4[(k << 12) + (h << 9) + tid];
    int i = tid << 1;
    lds2[swz(((i) << 3) | k)] = v2f{val.x, val.y};
    lds2[swz(((i + 1) << 3) | k)] = v2f{val.z, val.w};
  }
  __syncthreads();
  v2f s[NR];
#pragma unroll
  for (int v = 0; v < NR; ++v) s[v] = lds2[swz(MAP_A4(tid, v))];
  __syncthreads();

  // P0: reg bits 3..0 (T = bit)
  ROT(2, 13); ROT(1, 14); ROT(0, 15);          // R0 wires 13,14,15
  CNOTW(3, 2); CNOTW(2, 1); CNOTW(1, 0);       // C0 (12,13),(13,14),(14,15)
  ROT(3, 28); ROT(2, 29); ROT(1, 30); ROT(0, 31);  // R1 wires 12..15
  REMAP(MAP_A4, MAP_A3);
  // P1: reg bits 6..3 (T = bit-3)
  CNOTW(1, 0);      // C1 (11,12)  [bits 4,3]
  ROT(1, 43);       // R2 wire 11  [bit 4]
  CNOTW(2, 1);      // C2 (10,11)  [bits 5,4]
  ROT(2, 58);       // R3 wire 10  [bit 5]
  CNOTW(3, 2);      // C3 (9,10)   [bits 6,5]
  REMAP(MAP_A3, MAP_B2);
  // P2: reg bits 5..2 (T = bit-2)
  CNOTW(1, 0);      // C1 (12,13)  [bits 3,2]
  ROT(1, 44);       // R2 wire 12  [bit 3]
  CNOTW(2, 1);      // C2 (11,12)  [bits 4,3]
  ROT(2, 59);       // R3 wire 11  [bit 4]
  CNOTW(3, 2);      // C3 (10,11)  [bits 5,4]
  REMAP(MAP_B2, MAP_B3);
  // P3: reg bits 4..1 (T = bit-1)
  CNOTW(1, 0);      // C1 (13,14)  [bits 2,1]
  ROT(1, 45);       // R2 wire 13  [bit 2]
  CNOTW(2, 1);      // C2 (12,13)  [bits 3,2]
  ROT(2, 60);       // R3 wire 12  [bit 3]
  CNOTW(3, 2);      // C3 (11,12)  [bits 4,3]
  REMAP(MAP_B3, MAP_A4);
  // P4: reg bits 3..0 (T = bit)
  CNOTW(1, 0);                 // C1 (14,15)
  ROT(1, 46); ROT(0, 47);      // R2 wires 14,15
  CNOTW(2, 1); CNOTW(1, 0);    // C2 (13,14),(14,15)
  ROT(2, 61); ROT(1, 62); ROT(0, 63);  // R3 wires 13,14,15
  CNOTW(3, 2); CNOTW(2, 1); CNOTW(1, 0);  // C3 (12,13),(13,14),(14,15)

  // Epilogue (A4 arrangement): c = (t<<4)|v; v bits 3..0 = wires 12..15,
  // t bits 8..0 = wires 3..11 (wire q <-> t bit 11-q).
  float P = 0.f, f12 = 0.f, f13 = 0.f, f14 = 0.f, f15 = 0.f;
#pragma unroll
  for (int v = 0; v < NR; ++v) {
    float p = s[v][0] * s[v][0] + s[v][1] * s[v][1];
    P += p;
    f12 += ((v >> 3) & 1) ? -p : p;
    f13 += ((v >> 2) & 1) ? -p : p;
    f14 += ((v >> 1) & 1) ? -p : p;
    f15 += ((v >> 0) & 1) ? -p : p;
  }
  float vals[14];
  vals[0] = P;
#pragma unroll
  for (int q = 3; q <= 11; ++q)
    vals[q - 2] = ((tid >> (11 - q)) & 1) ? -P : P;
  vals[10] = f12; vals[11] = f13; vals[12] = f14; vals[13] = f15;

  const int lane = tid & 63, w = tid >> 6;
#pragma unroll
  for (int q = 0; q < 14; ++q) {
    float x = vals[q];
#pragma unroll
    for (int m = 1; m < 64; m <<= 1) x += __shfl_xor(x, m, 64);
    vals[q] = x;
  }
  float* red = (float*)lds2;
  if (lane == 0) {
#pragma unroll
    for (int q = 0; q < 14; ++q) red[q * 8 + w] = vals[q];
  }
  __syncthreads();
  if (tid < 14) {
    float F = 0.f;
#pragma unroll
    for (int ww = 0; ww < 8; ++ww) F += red[tid * 8 + ww];
    float* pt = partials + (size_t)blockIdx.x * 16;
    if (tid == 0) {
      pt[0] = (h & 4) ? -F : F;  // wire 0 <-> h bit 2
      pt[1] = (h & 2) ? -F : F;  // wire 1
      pt[2] = (h & 1) ? -F : F;  // wire 2
    } else {
      pt[tid + 2] = F;           // tid 1..9 -> wires 3..11; 10..13 -> 12..15
    }
  }
}

// ---------------------------------------------------------------------------
__global__ void k_head(const float* __restrict__ partials, const float* __restrict__ w,
                       const float* __restrict__ bh, float* __restrict__ out) {
  int b = threadIdx.x;  // 256 threads
  float acc = bh[0];
  for (int q = 0; q < 16; ++q) {
    float F = 0.f;
    for (int hh = 0; hh < 8; ++hh) F += partials[(size_t)(b * 8 + hh) * 16 + q];
    acc += w[q] * F;
  }
  out[b] = acc;
}

// ---------------------------------------------------------------------------
extern "C" void kernel_launch(void* const* d_in, const int* in_sizes, int n_in,
                              void* d_out, int out_size, void* d_ws, size_t ws_size,
                              hipStream_t stream) {
  const float* state  = (const float*)d_in[0];
  const float* params = (const float*)d_in[1];
  const float* w_head = (const float*)d_in[2];
  const float* b_head = (const float*)d_in[3];
  float* out = (float*)d_out;

  char* ws = (char*)d_ws;
  v2f* st = (v2f*)ws;                                       // 128 MB
  float4* Utab = (float4*)(ws + (size_t)134217728);         // 1 KB
  float* partials = (float*)(ws + (size_t)134217728 + 1024);

  k_setup<<<1, 64, 0, stream>>>(params, Utab);
  k_passA<<<dim3(2048), dim3(NT), 0, stream>>>(state, Utab, st);
  k_passB<<<dim3(2048), dim3(NT), 0, stream>>>(st, Utab, partials);
  k_head<<<1, 256, 0, stream>>>(partials, w_head, b_head, out);
}

// Round 3
// 209.413 us; speedup vs baseline: 1.0792x; 1.0271x over previous
//
#include <hip/hip_runtime.h>

typedef float v2f __attribute__((ext_vector_type(2)));

#define NT 512   // threads per block
#define NR 16    // v2f amplitudes per thread (4-bit register window)

// ---------------------------------------------------------------------------
// LDS swizzle: l ^ ((l>>5)&31).
__device__ __forceinline__ int swz(int l) { return l ^ ((l >> 5) & 31); }

// SU(2) rotation on a register pair: U = [[a, b], [-conj(b), conj(a)]]
__device__ __forceinline__ void rot2(v2f& x, v2f& y, v2f aa, v2f an, v2f bb, v2f bn) {
  v2f xs = __builtin_shufflevector(x, x, 1, 0);
  v2f ys = __builtin_shufflevector(y, y, 1, 0);
  v2f n0 = aa * x + an * xs + bb * y + bn * ys;
  v2f n1 = aa * y - an * ys + bn * xs - bb * x;
  x = n0;
  y = n1;
}

#define ROT(T, G)                                                              \
  do {                                                                         \
    const float4 u = Utab[G];                                                  \
    const v2f aa = {u.x, u.x}, an = {-u.y, u.y};                               \
    const v2f bb = {u.z, u.z}, bn = {-u.w, u.w};                               \
    _Pragma("unroll") for (int v = 0; v < NR; ++v) if (!((v >> (T)) & 1))      \
        rot2(s[v], s[v | (1 << (T))], aa, an, bb, bn);                         \
  } while (0)

// CNOT, both bits in window: compile-time register swap (zero instructions).
#define CNOTW(C, T)                                                            \
  do {                                                                         \
    _Pragma("unroll") for (int v = 0; v < NR; ++v)                             \
        if (((v >> (C)) & 1) && !((v >> (T)) & 1)) {                           \
      v2f tmp = s[v];                                                          \
      s[v] = s[v | (1 << (T))];                                                \
      s[v | (1 << (T))] = tmp;                                                 \
    }                                                                          \
  } while (0)

// Window maps: 13-bit local index from (t[8:0], reg v[3:0]).
// Wave bits of the LDS address (c[12:10]) are INVARIANT (= tid[8:6]) for
// A2, A3, A4, B2, B3 -> remaps among those are wave-local (no barrier).
// Only A1 (wave = c[8:6]) crosses waves.
#define MAP_A1(t, v) (((v) << 9) | (t))                               // reg = bits 12..9
#define MAP_A2(t, v) ((((t) >> 6) << 10) | ((v) << 6) | ((t) & 63))   // reg = bits 9..6
#define MAP_A3(t, v) ((((t) >> 3) << 7) | ((v) << 3) | ((t) & 7))     // reg = bits 6..3
#define MAP_A4(t, v) (((t) << 4) | (v))                               // reg = bits 3..0
#define MAP_B2(t, v) ((((t) >> 2) << 6) | ((v) << 2) | ((t) & 3))     // reg = bits 5..2
#define MAP_B3(t, v) ((((t) >> 1) << 5) | ((v) << 1) | ((t) & 1))     // reg = bits 4..1

#define REMAP_W(MW)                                                            \
  _Pragma("unroll") for (int r = 0; r < NR; ++r) lds2[swz(MW(tid, r))] = s[r]
#define REMAP_R(MR)                                                            \
  _Pragma("unroll") for (int v = 0; v < NR; ++v) s[v] = lds2[swz(MR(tid, v))]

// Wave-local remap: both maps keep wave = c[12:10]; per-wave in-order DS +
// compiler lgkmcnt give correctness. No barriers.
#define REMAP_L(MW, MR)  do { REMAP_W(MW); REMAP_R(MR); } while (0)
// Cross write (A1): all waves must be done reading before anyone writes A1.
#define REMAP_BWB(MW, MR) do { __syncthreads(); REMAP_W(MW); __syncthreads(); REMAP_R(MR); } while (0)
// Cross read (A1): own-region write, then barrier, then cross read.
#define REMAP_WB(MW, MR)  do { REMAP_W(MW); __syncthreads(); REMAP_R(MR); } while (0)

// ---------------------------------------------------------------------------
// Fused U = RZ @ RY @ RX per (layer, wire): (alpha_re, alpha_im, beta_re, beta_im)
__global__ void k_setup(const float* __restrict__ params, float4* __restrict__ Utab) {
  int g = threadIdx.x;
  if (g < 64) {
    float a = params[g * 3 + 0] * 0.5f;
    float b = params[g * 3 + 1] * 0.5f;
    float c = params[g * 3 + 2] * 0.5f;
    float sa, ca, sb, cb, sc, cc;
    sincosf(a, &sa, &ca);
    sincosf(b, &sb, &cb);
    sincosf(c, &sc, &cc);
    float X = cb * ca, Y = sb * sa;
    float Xp = -sb * ca, Yp = -cb * sa;
    Utab[g] = make_float4(cc * X + sc * Y, cc * Y - sc * X,
                          cc * Xp + sc * Yp, cc * Yp - sc * Xp);
  }
}

// ---------------------------------------------------------------------------
// Pass A: local wires 0..12 (orig bits 15..3); wire q <-> local bit 12-q.
__global__ __launch_bounds__(NT, 2) void k_passA(const float* __restrict__ in,
                                                 const float4* __restrict__ Utab,
                                                 v2f* __restrict__ st) {
  __shared__ v2f lds2[8192];
  const int tid = threadIdx.x;
  const int g = (blockIdx.x >> 3) & 7;
  const int b = ((blockIdx.x >> 6) << 3) | (blockIdx.x & 7);
  const float* base = in + (size_t)b * 65536;

  v2f s[NR];
#pragma unroll
  for (int v = 0; v < NR; ++v) {
    float re = base[(v << 12) + (tid << 3) + g];
    s[v] = v2f{re, 0.0f};
  }

#pragma unroll
  for (int l = 0; l < 4; ++l) {
    // W1: reg bits 12..9 = wires 0..3 (T = 3-q)
    ROT(3, l * 16 + 0); ROT(2, l * 16 + 1); ROT(1, l * 16 + 2); ROT(0, l * 16 + 3);
    CNOTW(3, 2); CNOTW(2, 1); CNOTW(1, 0);       // C_l (0,1),(1,2),(2,3)
    REMAP_BWB(MAP_A1, MAP_A2);                   // cross write, cross sync
    // W2: reg bits 9..6 = wires 3..6; rotations on 4,5,6 (T = 6-q)
    ROT(2, l * 16 + 4); ROT(1, l * 16 + 5); ROT(0, l * 16 + 6);
    CNOTW(3, 2); CNOTW(2, 1); CNOTW(1, 0);       // C_l (3,4),(4,5),(5,6)
    REMAP_L(MAP_A2, MAP_A3);                     // wave-local
    // W3: reg bits 6..3 = wires 6..9; rotations on 7,8,9 (T = 9-q)
    ROT(2, l * 16 + 7); ROT(1, l * 16 + 8); ROT(0, l * 16 + 9);
    CNOTW(3, 2); CNOTW(2, 1); CNOTW(1, 0);       // C_l (6,7),(7,8),(8,9)
    if (l < 3) {
      REMAP_L(MAP_A3, MAP_A4);                   // wave-local
      // W4: reg bits 3..0 = wires 9..12 (T = 12-q); staircase tail
      ROT(2, l * 16 + 10);
      if (l <= 1) ROT(1, l * 16 + 11);
      if (l == 0) ROT(0, l * 16 + 12);
      CNOTW(3, 2);
      if (l <= 1) CNOTW(2, 1);
      if (l == 0) CNOTW(1, 0);
      REMAP_WB(MAP_A4, MAP_A1);                  // own write, barrier, cross read
    }
  }

  // Store bounce (from A3 arrangement, own-region write; linear read crosses).
  REMAP_W(MAP_A3);
  __syncthreads();
  float4* outp = (float4*)(st + (size_t)(b * 8 + g) * 8192);
#pragma unroll
  for (int k = 0; k < 8; ++k) {
    int o = (k << 10) + (tid << 1);
    v2f a0 = lds2[swz(o)], a1 = lds2[swz(o + 1)];
    outp[(k << 9) + tid] = make_float4(a0[0], a0[1], a1[0], a1[1]);
  }
}

// ---------------------------------------------------------------------------
// Pass B: local wires 3..15 (orig bits 12..0); wire q <-> local bit 15-q.
// Entry write and all remaps are wave-local (wave = c[12:10] throughout).
__global__ __launch_bounds__(NT, 2) void k_passB(const v2f* __restrict__ st,
                                                 const float4* __restrict__ Utab,
                                                 float* __restrict__ partials) {
  __shared__ v2f lds2[8192];
  const int tid = threadIdx.x;
  const int b = blockIdx.x >> 3;
  const int h = blockIdx.x & 7;  // orig bits 15..13
  const float4* base4 = (const float4*)(st + (size_t)b * 65536);

  // Coalesced float4 load; element i of chunk k has c = (i<<3)|k.
  // c bits 12..10 = tid[8:6] -> own-region write, no barrier needed.
#pragma unroll
  for (int k = 0; k < 8; ++k) {
    float4 val = base4[(k << 12) + (h << 9) + tid];
    int i = tid << 1;
    lds2[swz(((i) << 3) | k)] = v2f{val.x, val.y};
    lds2[swz(((i + 1) << 3) | k)] = v2f{val.z, val.w};
  }
  v2f s[NR];
  REMAP_R(MAP_A4);  // own-region read

  // P0: reg bits 3..0 (T = bit)
  ROT(2, 13); ROT(1, 14); ROT(0, 15);          // R0 wires 13,14,15
  CNOTW(3, 2); CNOTW(2, 1); CNOTW(1, 0);       // C0 (12,13),(13,14),(14,15)
  ROT(3, 28); ROT(2, 29); ROT(1, 30); ROT(0, 31);  // R1 wires 12..15
  REMAP_L(MAP_A4, MAP_A3);
  // P1: reg bits 6..3 (T = bit-3)
  CNOTW(1, 0);      // C1 (11,12)
  ROT(1, 43);       // R2 wire 11
  CNOTW(2, 1);      // C2 (10,11)
  ROT(2, 58);       // R3 wire 10
  CNOTW(3, 2);      // C3 (9,10)
  REMAP_L(MAP_A3, MAP_B2);
  // P2: reg bits 5..2 (T = bit-2)
  CNOTW(1, 0);      // C1 (12,13)
  ROT(1, 44);       // R2 wire 12
  CNOTW(2, 1);      // C2 (11,12)
  ROT(2, 59);       // R3 wire 11
  CNOTW(3, 2);      // C3 (10,11)
  REMAP_L(MAP_B2, MAP_B3);
  // P3: reg bits 4..1 (T = bit-1)
  CNOTW(1, 0);      // C1 (13,14)
  ROT(1, 45);       // R2 wire 13
  CNOTW(2, 1);      // C2 (12,13)
  ROT(2, 60);       // R3 wire 12
  CNOTW(3, 2);      // C3 (11,12)
  REMAP_L(MAP_B3, MAP_A4);
  // P4: reg bits 3..0 (T = bit)
  CNOTW(1, 0);                 // C1 (14,15)
  ROT(1, 46); ROT(0, 47);      // R2 wires 14,15
  CNOTW(2, 1); CNOTW(1, 0);    // C2 (13,14),(14,15)
  ROT(2, 61); ROT(1, 62); ROT(0, 63);  // R3 wires 13,14,15
  CNOTW(3, 2); CNOTW(2, 1); CNOTW(1, 0);  // C3 (12,13),(13,14),(14,15)

  // Epilogue (A4 arrangement): c = (t<<4)|v; v bits 3..0 = wires 12..15,
  // t bits 8..0 = wires 3..11 (wire q <-> t bit 11-q).
  float P = 0.f, f12 = 0.f, f13 = 0.f, f14 = 0.f, f15 = 0.f;
#pragma unroll
  for (int v = 0; v < NR; ++v) {
    float p = s[v][0] * s[v][0] + s[v][1] * s[v][1];
    P += p;
    f12 += ((v >> 3) & 1) ? -p : p;
    f13 += ((v >> 2) & 1) ? -p : p;
    f14 += ((v >> 1) & 1) ? -p : p;
    f15 += ((v >> 0) & 1) ? -p : p;
  }
  float vals[14];
  vals[0] = P;
#pragma unroll
  for (int q = 3; q <= 11; ++q)
    vals[q - 2] = ((tid >> (11 - q)) & 1) ? -P : P;
  vals[10] = f12; vals[11] = f13; vals[12] = f14; vals[13] = f15;

  const int lane = tid & 63, w = tid >> 6;
#pragma unroll
  for (int q = 0; q < 14; ++q) {
    float x = vals[q];
#pragma unroll
    for (int m = 1; m < 64; m <<= 1) x += __shfl_xor(x, m, 64);
    vals[q] = x;
  }
  // red[] lives in wave-0's LDS region -> must sync all waves' prior reads.
  __syncthreads();
  float* red = (float*)lds2;
  if (lane == 0) {
#pragma unroll
    for (int q = 0; q < 14; ++q) red[q * 8 + w] = vals[q];
  }
  __syncthreads();
  if (tid < 14) {
    float F = 0.f;
#pragma unroll
    for (int ww = 0; ww < 8; ++ww) F += red[tid * 8 + ww];
    float* pt = partials + (size_t)blockIdx.x * 16;
    if (tid == 0) {
      pt[0] = (h & 4) ? -F : F;  // wire 0 <-> h bit 2
      pt[1] = (h & 2) ? -F : F;  // wire 1
      pt[2] = (h & 1) ? -F : F;  // wire 2
    } else {
      pt[tid + 2] = F;           // tid 1..9 -> wires 3..11; 10..13 -> 12..15
    }
  }
}

// ---------------------------------------------------------------------------
__global__ void k_head(const float* __restrict__ partials, const float* __restrict__ w,
                       const float* __restrict__ bh, float* __restrict__ out) {
  int b = threadIdx.x;  // 256 threads
  float acc = bh[0];
  for (int q = 0; q < 16; ++q) {
    float F = 0.f;
    for (int hh = 0; hh < 8; ++hh) F += partials[(size_t)(b * 8 + hh) * 16 + q];
    acc += w[q] * F;
  }
  out[b] = acc;
}

// ---------------------------------------------------------------------------
extern "C" void kernel_launch(void* const* d_in, const int* in_sizes, int n_in,
                              void* d_out, int out_size, void* d_ws, size_t ws_size,
                              hipStream_t stream) {
  const float* state  = (const float*)d_in[0];
  const float* params = (const float*)d_in[1];
  const float* w_head = (const float*)d_in[2];
  const float* b_head = (const float*)d_in[3];
  float* out = (float*)d_out;

  char* ws = (char*)d_ws;
  v2f* st = (v2f*)ws;                                       // 128 MB
  float4* Utab = (float4*)(ws + (size_t)134217728);         // 1 KB
  float* partials = (float*)(ws + (size_t)134217728 + 1024);

  k_setup<<<1, 64, 0, stream>>>(params, Utab);
  k_passA<<<dim3(2048), dim3(NT), 0, stream>>>(state, Utab, st);
  k_passB<<<dim3(2048), dim3(NT), 0, stream>>>(st, Utab, partials);
  k_head<<<1, 256, 0, stream>>>(partials, w_head, b_head, out);
}